// Round 1
// baseline (536.796 us; speedup 1.0000x reference)
//
#include <hip/hip_runtime.h>
#include <stdint.h>

// Problem constants (from reference)
#define DM    1024   // d_model
#define DFFN  4096
#define NTOK  4096   // N*T = 2*2048
#define TT    2048
#define NHEAD 16
#define HD    64
#define LN_EPS 1e-3f

typedef float  f32x4  __attribute__((ext_vector_type(4)));
typedef __bf16 bf16x8 __attribute__((ext_vector_type(8)));

using void_as1 = __attribute__((address_space(1))) void;
using void_as3 = __attribute__((address_space(3))) void;

__device__ __forceinline__ void g2l16(const void* g, void* l) {
    // async global->LDS, 16B per lane; lane i lands at ldsbase + i*16
    __builtin_amdgcn_global_load_lds((const void_as1*)g, (void_as3*)l, 16, 0, 0);
}

__device__ __forceinline__ unsigned short f2bf(float f) {
    unsigned u = __builtin_bit_cast(unsigned, f);
    u += 0x7FFFu + ((u >> 16) & 1u);   // RNE
    return (unsigned short)(u >> 16);
}

// ---------------- elementwise cast f32 -> bf16 ----------------
__global__ __launch_bounds__(256) void cast_bf16_kernel(
    const float* __restrict__ in, unsigned short* __restrict__ out, int n4) {
    int i = blockIdx.x * 256 + threadIdx.x;
    if (i < n4) {
        float4 v = ((const float4*)in)[i];
        ushort4 o;
        o.x = f2bf(v.x); o.y = f2bf(v.y); o.z = f2bf(v.z); o.w = f2bf(v.w);
        ((ushort4*)out)[i] = o;
    }
}

// ---------------- transpose + cast: w[K][Nc] f32 -> wT[Nc][K] bf16 ----------
__global__ __launch_bounds__(256) void transpose_cast_kernel(
    const float* __restrict__ w, unsigned short* __restrict__ wT, int K, int Nc) {
    __shared__ float tile[32][33];
    int tx = threadIdx.x & 31, ty = threadIdx.x >> 5;
    int n0 = blockIdx.x * 32, k0 = blockIdx.y * 32;
#pragma unroll
    for (int i = 0; i < 4; ++i)
        tile[ty + 8 * i][tx] = w[(size_t)(k0 + ty + 8 * i) * Nc + (n0 + tx)];
    __syncthreads();
#pragma unroll
    for (int i = 0; i < 4; ++i)
        wT[(size_t)(n0 + ty + 8 * i) * K + (k0 + tx)] = f2bf(tile[tx][ty + 8 * i]);
}

// ---------------- bt-GEMM: C[M,Nc] = A[M,K] @ Bt[Nc,K]^T  (bf16, f32 acc) ---
// EPI 0: +bias, de-interleave qkv -> q[NH,T,D], k[NH,T,D], vT[NH,D,T] (bf16)
// EPI 1: +bias, relu -> bf16 (ldc = DFFN)
// EPI 2: +bias -> f32 (ldc = DM)
template <int EPI>
__global__ __launch_bounds__(256, 2) void gemm_bt_kernel(
    const unsigned short* __restrict__ A,
    const unsigned short* __restrict__ Bt,
    const float* __restrict__ bias,
    unsigned short* __restrict__ oq,
    unsigned short* __restrict__ ok,
    unsigned short* __restrict__ ov,
    float* __restrict__ of,
    int M, int Ncols, int K) {
    __shared__ unsigned short As[128 * 32];
    __shared__ unsigned short Bs[128 * 32];
    const int tid  = threadIdx.x;
    const int wave = tid >> 6, lane = tid & 63;
    const int quad = lane >> 4, l16 = lane & 15;
    const int wm = wave >> 1, wn = wave & 1;
    const int mBase = blockIdx.x * 128, nBase = blockIdx.y * 128;

    f32x4 acc[4][4] = {};

    for (int k0 = 0; k0 < K; k0 += 32) {
#pragma unroll
        for (int i = 0; i < 2; ++i) {
            const int chunk = i * 256 + tid;      // 0..511, 16B each
            const int row = chunk >> 2, kc = chunk & 3;
            g2l16(A  + (size_t)(mBase + row) * K + (k0 + kc * 8),
                  (char*)As + (size_t)(i * 256 + wave * 64) * 16);
            g2l16(Bt + (size_t)(nBase + row) * K + (k0 + kc * 8),
                  (char*)Bs + (size_t)(i * 256 + wave * 64) * 16);
        }
        __syncthreads();   // drains vmcnt before barrier -> LDS tiles ready
        bf16x8 af[4], bfr[4];
#pragma unroll
        for (int i = 0; i < 4; ++i)
            af[i] = *(const bf16x8*)(const void*)(As + (wm * 64 + i * 16 + l16) * 32 + quad * 8);
#pragma unroll
        for (int j = 0; j < 4; ++j)
            bfr[j] = *(const bf16x8*)(const void*)(Bs + (wn * 64 + j * 16 + l16) * 32 + quad * 8);
#pragma unroll
        for (int i = 0; i < 4; ++i)
#pragma unroll
            for (int j = 0; j < 4; ++j)
                acc[i][j] = __builtin_amdgcn_mfma_f32_16x16x32_bf16(af[i], bfr[j], acc[i][j], 0, 0, 0);
        __syncthreads();   // all waves done reading before next overwrite
    }

    // Epilogue. C/D layout: col = lane&15, row = quad*4 + reg (m89-verified)
#pragma unroll
    for (int i = 0; i < 4; ++i) {
        const int rbase = mBase + wm * 64 + i * 16 + quad * 4;
#pragma unroll
        for (int j = 0; j < 4; ++j) {
            const int col = nBase + wn * 64 + j * 16 + l16;
            const float bv = bias[col];
#pragma unroll
            for (int r = 0; r < 4; ++r) {
                const int row = rbase + r;
                const float v = acc[i][j][r] + bv;
                if (EPI == 0) {
                    // col = h*192 + d*3 + s  (reshape(N,T,H,D,3))
                    const int h = col / 192;
                    const int rem = col - h * 192;
                    const int d = rem / 3;
                    const int s = rem - d * 3;
                    const int n = row >> 11, t = row & (TT - 1);
                    const int nh = n * NHEAD + h;
                    if (s == 0)
                        oq[((size_t)nh * TT + t) * HD + d] = f2bf(v);
                    else if (s == 1)
                        ok[((size_t)nh * TT + t) * HD + d] = f2bf(v);
                    else
                        ov[((size_t)nh * HD + d) * TT + t] = f2bf(v);
                } else if (EPI == 1) {
                    oq[(size_t)row * DFFN + col] = f2bf(fmaxf(v, 0.0f));
                } else {
                    of[(size_t)row * DM + col] = v;
                }
            }
        }
    }
}

// ---------------- flash attention ----------------
// grid: 1024 blocks = (nh in 0..31) * (qt in 0..31); 4 waves, 16 q-rows each.
// q,k: [NH*N][T][D] bf16 ; vT: [NH*N][D][T] bf16 ; ctx out: [N*T][DM] f32
__global__ __launch_bounds__(256, 2) void attn_kernel(
    const unsigned short* __restrict__ q,
    const unsigned short* __restrict__ k,
    const unsigned short* __restrict__ vt,
    float* __restrict__ ctx) {
    __shared__ unsigned short Plds[4][16 * 128];
    const int tid  = threadIdx.x;
    const int wave = tid >> 6, lane = tid & 63;
    const int quad = lane >> 4, l16 = lane & 15;
    const int qt = blockIdx.x & 31;
    const int nh = blockIdx.x >> 5;    // n*16 + h
    const unsigned short* qh = q  + (size_t)nh * TT * HD;
    const unsigned short* kh = k  + (size_t)nh * TT * HD;
    const unsigned short* vh = vt + (size_t)nh * HD * TT;

    const int qrow = qt * 64 + wave * 16;
    // A-frag: A[m=lane&15][kdim=quad*8+j]
    const bf16x8 qa0 = *(const bf16x8*)(const void*)(qh + (size_t)(qrow + l16) * HD + quad * 8);
    const bf16x8 qa1 = *(const bf16x8*)(const void*)(qh + (size_t)(qrow + l16) * HD + 32 + quad * 8);

    f32x4 o[4] = {};
    float m[4] = {-1e30f, -1e30f, -1e30f, -1e30f};
    float l[4] = {0.f, 0.f, 0.f, 0.f};
    unsigned short* pw = &Plds[wave][0];

    for (int kt = 0; kt < TT; kt += 128) {
        // S = (Q K^T) * 1/8, tile 16 x 128 per wave
        f32x4 s[8];
#pragma unroll
        for (int c = 0; c < 8; ++c) {
            const unsigned short* kp = kh + (size_t)(kt + c * 16 + l16) * HD;
            bf16x8 kb0 = *(const bf16x8*)(const void*)(kp + quad * 8);
            bf16x8 kb1 = *(const bf16x8*)(const void*)(kp + 32 + quad * 8);
            f32x4 z = {};
            z = __builtin_amdgcn_mfma_f32_16x16x32_bf16(qa0, kb0, z, 0, 0, 0);
            z = __builtin_amdgcn_mfma_f32_16x16x32_bf16(qa1, kb1, z, 0, 0, 0);
            s[c] = z * 0.125f;
        }
        // online softmax over the 128 new cols (mask is a per-row constant -> no-op)
        float nm[4], alpha[4], rs[4];
#pragma unroll
        for (int r = 0; r < 4; ++r) {
            float mx = s[0][r];
#pragma unroll
            for (int c = 1; c < 8; ++c) mx = fmaxf(mx, s[c][r]);
            mx = fmaxf(mx, __shfl_xor(mx, 1, 64));
            mx = fmaxf(mx, __shfl_xor(mx, 2, 64));
            mx = fmaxf(mx, __shfl_xor(mx, 4, 64));
            mx = fmaxf(mx, __shfl_xor(mx, 8, 64));
            nm[r]    = fmaxf(m[r], mx);
            alpha[r] = __expf(m[r] - nm[r]);
            m[r]     = nm[r];
            rs[r]    = 0.f;
        }
#pragma unroll
        for (int c = 0; c < 8; ++c)
#pragma unroll
            for (int r = 0; r < 4; ++r) {
                float p = __expf(s[c][r] - nm[r]);
                s[c][r] = p;
                rs[r] += p;
            }
#pragma unroll
        for (int r = 0; r < 4; ++r) {
            float t = rs[r];
            t += __shfl_xor(t, 1, 64);
            t += __shfl_xor(t, 2, 64);
            t += __shfl_xor(t, 4, 64);
            t += __shfl_xor(t, 8, 64);
            l[r] = l[r] * alpha[r] + t;
            o[0][r] *= alpha[r]; o[1][r] *= alpha[r];
            o[2][r] *= alpha[r]; o[3][r] *= alpha[r];
        }
        // P (C-layout) -> per-wave LDS -> A-layout frags
#pragma unroll
        for (int c = 0; c < 8; ++c)
#pragma unroll
            for (int r = 0; r < 4; ++r)
                pw[(quad * 4 + r) * 128 + c * 16 + l16] = f2bf(s[c][r]);
        asm volatile("s_waitcnt lgkmcnt(0)" ::: "memory");  // wave-local W->R ordering
#pragma unroll
        for (int kc = 0; kc < 4; ++kc) {
            bf16x8 pa = *(const bf16x8*)(const void*)(pw + l16 * 128 + kc * 32 + quad * 8);
#pragma unroll
            for (int dc = 0; dc < 4; ++dc) {
                bf16x8 vb = *(const bf16x8*)(const void*)(vh + (size_t)(dc * 16 + l16) * TT + kt + kc * 32 + quad * 8);
                o[dc] = __builtin_amdgcn_mfma_f32_16x16x32_bf16(pa, vb, o[dc], 0, 0, 0);
            }
        }
    }
    const int n = nh >> 4, h = nh & 15;
#pragma unroll
    for (int r = 0; r < 4; ++r) {
        const int trow = qrow + quad * 4 + r;
        const float inv = 1.0f / l[r];
        float* op = ctx + ((size_t)(n * TT + trow)) * DM + h * HD;
#pragma unroll
        for (int dc = 0; dc < 4; ++dc)
            op[dc * 16 + l16] = o[dc][r] * inv;
    }
}

// ---------------- fused add + layernorm ----------------
// out = LN(a + b) * gamma + beta ; optional bf16 copy
__global__ __launch_bounds__(256) void add_ln_kernel(
    const float* __restrict__ a, const float* __restrict__ b,
    const float* __restrict__ gamma, const float* __restrict__ beta,
    float* __restrict__ outf, unsigned short* __restrict__ outb) {
    const int row = blockIdx.x;
    const int tid = threadIdx.x;
    const int lane = tid & 63, wave = tid >> 6;
    const float4 av = ((const float4*)(a + (size_t)row * DM))[tid];
    const float4 bv = ((const float4*)(b + (size_t)row * DM))[tid];
    float4 x;
    x.x = av.x + bv.x; x.y = av.y + bv.y; x.z = av.z + bv.z; x.w = av.w + bv.w;
    float s = x.x + x.y + x.z + x.w;
    float q = x.x * x.x + x.y * x.y + x.z * x.z + x.w * x.w;
#pragma unroll
    for (int off = 1; off < 64; off <<= 1) {
        s += __shfl_xor(s, off, 64);
        q += __shfl_xor(q, off, 64);
    }
    __shared__ float sh[8];
    if (lane == 0) { sh[wave] = s; sh[4 + wave] = q; }
    __syncthreads();
    s = sh[0] + sh[1] + sh[2] + sh[3];
    q = sh[4] + sh[5] + sh[6] + sh[7];
    const float mu = s * (1.0f / DM);
    const float var = q * (1.0f / DM) - mu * mu;
    const float rstd = rsqrtf(var + LN_EPS);
    const float4 g4 = ((const float4*)gamma)[tid];
    const float4 b4 = ((const float4*)beta)[tid];
    float4 o;
    o.x = (x.x - mu) * rstd * g4.x + b4.x;
    o.y = (x.y - mu) * rstd * g4.y + b4.y;
    o.z = (x.z - mu) * rstd * g4.z + b4.z;
    o.w = (x.w - mu) * rstd * g4.w + b4.w;
    ((float4*)(outf + (size_t)row * DM))[tid] = o;
    if (outb) {
        ushort4 ob;
        ob.x = f2bf(o.x); ob.y = f2bf(o.y); ob.z = f2bf(o.z); ob.w = f2bf(o.w);
        ((ushort4*)(outb + (size_t)row * DM))[tid] = ob;
    }
}

extern "C" void kernel_launch(void* const* d_in, const int* in_sizes, int n_in,
                              void* d_out, int out_size, void* d_ws, size_t ws_size,
                              hipStream_t stream) {
    const float* x     = (const float*)d_in[0];
    // d_in[1] = mask: provably a softmax no-op (constant per query row) -> unused
    const float* w_qkv = (const float*)d_in[2];
    const float* b_qkv = (const float*)d_in[3];
    const float* w_ff  = (const float*)d_in[4];
    const float* b_ff  = (const float*)d_in[5];
    const float* w_out = (const float*)d_in[6];
    const float* b_out = (const float*)d_in[7];
    const float* ln1_g = (const float*)d_in[8];
    const float* ln1_b = (const float*)d_in[9];
    const float* ln2_g = (const float*)d_in[10];
    const float* ln2_b = (const float*)d_in[11];

    // workspace layout (bytes), total ~142 MB
    char* ws = (char*)d_ws;
    unsigned short* xb    = (unsigned short*)(ws);                    // 8 MB
    unsigned short* wqkvT = (unsigned short*)(ws + 8388608);          // 6 MB
    unsigned short* wffT  = (unsigned short*)(ws + 14680064);         // 8 MB
    unsigned short* woutT = (unsigned short*)(ws + 23068672);         // 8 MB
    unsigned short* qb    = (unsigned short*)(ws + 31457280);         // 8 MB
    unsigned short* kb    = (unsigned short*)(ws + 39845888);         // 8 MB
    unsigned short* vtb   = (unsigned short*)(ws + 48234496);         // 8 MB
    float*          ctx   = (float*)(ws + 56623104);                  // 16 MB
    float*          hbuf  = (float*)(ws + 73400320);                  // 16 MB
    unsigned short* hb    = (unsigned short*)(ws + 90177536);         // 8 MB
    unsigned short* ffb   = (unsigned short*)(ws + 98566144);         // 32 MB
    float*          tmp   = (float*)(ws + 132120576);                 // 16 MB

    // 1) casts / weight transposes
    cast_bf16_kernel<<<(NTOK * DM / 4 + 255) / 256, 256, 0, stream>>>(x, xb, NTOK * DM / 4);
    transpose_cast_kernel<<<dim3(3072 / 32, DM / 32), 256, 0, stream>>>(w_qkv, wqkvT, DM, 3072);
    transpose_cast_kernel<<<dim3(DFFN / 32, DM / 32), 256, 0, stream>>>(w_ff, wffT, DM, DFFN);
    transpose_cast_kernel<<<dim3(DM / 32, DFFN / 32), 256, 0, stream>>>(w_out, woutT, DFFN, DM);

    // 2) QKV projection + de-interleave
    gemm_bt_kernel<0><<<dim3(NTOK / 128, 3072 / 128), 256, 0, stream>>>(
        xb, wqkvT, b_qkv, qb, kb, vtb, nullptr, NTOK, 3072, DM);

    // 3) attention -> ctx
    attn_kernel<<<32 * 32, 256, 0, stream>>>(qb, kb, vtb, ctx);

    // 4) h = LN(x + ctx)
    add_ln_kernel<<<NTOK, 256, 0, stream>>>(x, ctx, ln1_g, ln1_b, hbuf, hb);

    // 5) ff = relu(h @ w_ff + b_ff)
    gemm_bt_kernel<1><<<dim3(NTOK / 128, DFFN / 128), 256, 0, stream>>>(
        hb, wffT, b_ff, ffb, nullptr, nullptr, nullptr, NTOK, DFFN, DM);

    // 6) tmp = ff @ w_out + b_out
    gemm_bt_kernel<2><<<dim3(NTOK / 128, DM / 128), 256, 0, stream>>>(
        ffb, woutT, b_out, nullptr, nullptr, nullptr, tmp, NTOK, DM, DFFN);

    // 7) out = LN(h + tmp)
    add_ln_kernel<<<NTOK, 256, 0, stream>>>(hbuf, tmp, ln2_g, ln2_b, (float*)d_out, nullptr);
}